// Round 6
// baseline (291.638 us; speedup 1.0000x reference)
//
#include <hip/hip_runtime.h>
#include <math.h>

// B=4, T=2048, E=1024, H*D=1024; R = B*T = 8192.  K is always 1024.
#define R_ROWS 8192
#define T_SEQ  2048
#define E_DIM  1024
#define KC     32          // K/32 chunks

typedef __attribute__((ext_vector_type(8))) short short8;
typedef __attribute__((ext_vector_type(4))) float f32x4;

__device__ __forceinline__ ushort f2bf(float f) {
  uint u = __float_as_uint(f);
  u += 0x7FFFu + ((u >> 16) & 1u);   // round-to-nearest-even
  return (ushort)(u >> 16);
}
__device__ __forceinline__ float bf2f(ushort h) {
  return __uint_as_float(((uint)h) << 16);
}

// ---------------------------------------------------------------------------
// MFMA A/B fragment layout for a [R][1024] bf16 matrix:
//   off(r,k) = (((r>>4)*KC + (k>>5))*4 + ((k>>3)&3))*128 + (r&15)*8 + (k&7)
// ---------------------------------------------------------------------------

__global__ __launch_bounds__(256) void cvt_split_frag(
    const float* __restrict__ in, ushort* __restrict__ hi,
    ushort* __restrict__ lo, int n)
{
  int g = blockIdx.x * 256 + threadIdx.x;
  if (g >= n) return;
  const int l = g & 15, h = (g >> 4) & 3;
  const int pq = g >> 6;
  const int q = pq & (KC - 1), p = pq >> 5;
  const size_t src = (size_t)(p * 16 + l) * 1024 + q * 32 + h * 8;
  const float4 v0 = *(const float4*)&in[src];
  const float4 v1 = *(const float4*)&in[src + 4];
  ushort hh[8], ll[8];
  const float v[8] = {v0.x, v0.y, v0.z, v0.w, v1.x, v1.y, v1.z, v1.w};
#pragma unroll
  for (int e = 0; e < 8; ++e) {
    hh[e] = f2bf(v[e]);
    ll[e] = f2bf(v[e] - bf2f(hh[e]));
  }
  *(uint4*)&hi[(size_t)g * 8] = *(const uint4*)hh;
  *(uint4*)&lo[(size_t)g * 8] = *(const uint4*)ll;
}

__global__ __launch_bounds__(256) void cvt_bf16_frag(
    const float* __restrict__ in, ushort* __restrict__ out, int n)
{
  int g = blockIdx.x * 256 + threadIdx.x;
  if (g >= n) return;
  const int l = g & 15, h = (g >> 4) & 3;
  const int pq = g >> 6;
  const int q = pq & (KC - 1), p = pq >> 5;
  const size_t src = (size_t)(p * 16 + l) * 1024 + q * 32 + h * 8;
  const float4 v0 = *(const float4*)&in[src];
  const float4 v1 = *(const float4*)&in[src + 4];
  ushort hh[8];
  const float v[8] = {v0.x, v0.y, v0.z, v0.w, v1.x, v1.y, v1.z, v1.w};
#pragma unroll
  for (int e = 0; e < 8; ++e) hh[e] = f2bf(v[e]);
  *(uint4*)&out[(size_t)g * 8] = *(const uint4*)hh;
}

__global__ __launch_bounds__(256) void cvt_bf16(
    const float* __restrict__ in, ushort* __restrict__ out, int n4)
{
  int i = blockIdx.x * 256 + threadIdx.x;
  if (i >= n4) return;
  float4 v = ((const float4*)in)[i];
  ushort4 o;
  o.x = f2bf(v.x); o.y = f2bf(v.y); o.z = f2bf(v.z); o.w = f2bf(v.w);
  ((ushort4*)out)[i] = o;
}

// ---------------------------------------------------------------------------
// Split-bf16 sc kernel, LDS-free K-loop (unchanged from round 5).
// ---------------------------------------------------------------------------
struct Frags { short8 ah[4], al[4], bh[4], bl[4]; };

__global__ __launch_bounds__(256, 2) void gemm_sq_direct(
    const ushort* __restrict__ xh, const ushort* __restrict__ xl,
    const ushort* __restrict__ wh, const ushort* __restrict__ wl,
    float* __restrict__ sc_raw)
{
  const int tid = threadIdx.x;
  const int m0 = blockIdx.y * 128, n0 = blockIdx.x * 128;
  const int wave = tid >> 6, lane = tid & 63;
  const int l15 = lane & 15, lq = lane >> 4;
  const int wm = (wave & 1) * 64, wn = (wave >> 1) * 64;

  size_t aoff[4], boff[4];
#pragma unroll
  for (int i = 0; i < 4; ++i)
    aoff[i] = ((size_t)(((m0 + wm) >> 4) + i) * KC * 4 + lq) * 128 + l15 * 8;
#pragma unroll
  for (int j = 0; j < 4; ++j)
    boff[j] = ((size_t)(((n0 + wn) >> 4) + j) * KC * 4 + lq) * 128 + l15 * 8;

  f32x4 acc[4][4] = {};
  Frags f0, f1;

  auto load = [&](Frags& f, int q) {
    const size_t dq = (size_t)q * 512;
#pragma unroll
    for (int i = 0; i < 4; ++i) {
      f.ah[i] = *(const short8*)(xh + aoff[i] + dq);
      f.al[i] = *(const short8*)(xl + aoff[i] + dq);
    }
#pragma unroll
    for (int j = 0; j < 4; ++j) {
      f.bh[j] = *(const short8*)(wh + boff[j] + dq);
      f.bl[j] = *(const short8*)(wl + boff[j] + dq);
    }
  };
  auto step = [&](const Frags& f) {
#pragma unroll
    for (int i = 0; i < 4; ++i)
#pragma unroll
      for (int j = 0; j < 4; ++j) {
        acc[i][j] = __builtin_amdgcn_mfma_f32_16x16x32_bf16(f.ah[i], f.bh[j], acc[i][j], 0, 0, 0);
        acc[i][j] = __builtin_amdgcn_mfma_f32_16x16x32_bf16(f.ah[i], f.bl[j], acc[i][j], 0, 0, 0);
        acc[i][j] = __builtin_amdgcn_mfma_f32_16x16x32_bf16(f.al[i], f.bh[j], acc[i][j], 0, 0, 0);
      }
  };

  load(f0, 0);
#pragma unroll 1
  for (int q = 0; q < KC; q += 2) {
    load(f1, q + 1);
    step(f0);
    if (q + 2 < KC) load(f0, q + 2);
    step(f1);
  }

  __shared__ float red[128][33];
#pragma unroll
  for (int i = 0; i < 4; ++i)
#pragma unroll
    for (int r = 0; r < 4; ++r) {
      const int row = wm + i * 16 + lq * 4 + r;
      float s = 0.f;
#pragma unroll
      for (int j = 0; j < 4; ++j) s += acc[i][j][r] * acc[i][j][r];
      red[row][(l15 << 1) | (wave >> 1)] = s;
    }
  __syncthreads();
  if (tid < 128) {
    float s = 0.f;
#pragma unroll
    for (int c = 0; c < 32; ++c) s += red[tid][c];
    atomicAdd(&sc_raw[m0 + tid], s);
  }
}

// ---------------------------------------------------------------------------
// sc = sc_raw/32; pmax = inclusive prefix max per batch.
// ---------------------------------------------------------------------------
__global__ __launch_bounds__(1024) void scan_max(
    const float* __restrict__ sc_raw, float* __restrict__ sc,
    float* __restrict__ pmax)
{
  const int b = blockIdx.x;
  __shared__ float b0[T_SEQ];
  __shared__ float b1[T_SEQ];
  const int tid = threadIdx.x;
  for (int i = tid; i < T_SEQ; i += 1024) {
    const float v = sc_raw[b*T_SEQ + i] * 0.03125f;
    b0[i] = v;
    sc[b*T_SEQ + i] = v;
  }
  __syncthreads();
  float* src = b0; float* dst = b1;
  for (int off = 1; off < T_SEQ; off <<= 1) {
    for (int i = tid; i < T_SEQ; i += 1024)
      dst[i] = (i >= off) ? fmaxf(src[i], src[i - off]) : src[i];
    __syncthreads();
    float* tmp = src; src = dst; dst = tmp;
  }
  for (int i = tid; i < T_SEQ; i += 1024) pmax[b*T_SEQ + i] = src[i];
}

// ---------------------------------------------------------------------------
// P generation: causal band of P = exp(sc_t*(sc_s - pmax_t)), bf16, written
// ONCE in MFMA A-fragment layout. Chunk-block = 128t x 64s = 8192 ushorts.
// Per batch: tile ty has 2ty+2 chunks, prefix ty*(ty+1), total 272.
// Also accumulates Z[t] = row sums (of the bf16-rounded P) via atomics.
// ---------------------------------------------------------------------------
__global__ __launch_bounds__(256) void pgen(
    const float* __restrict__ sc, const float* __restrict__ pmax,
    ushort* __restrict__ Pfrag, float* __restrict__ Z)
{
  const int b = blockIdx.y;
  const int cb = blockIdx.x;            // 0..271
  int ty = (int)((sqrtf(4.0f * cb + 1.0f) - 1.0f) * 0.5f);
  while ((ty + 1) * (ty + 2) <= cb) ++ty;
  while (ty * (ty + 1) > cb) --ty;
  const int c = cb - ty * (ty + 1);
  const int t0 = ty * 128, s0 = c * 64;
  const int bT = b * T_SEQ;
  const int tid = threadIdx.x;

  __shared__ float stv[128], pmv[128], scs[64], zacc[128];
  if (tid < 128) {
    stv[tid] = sc[bT + t0 + tid];
    pmv[tid] = pmax[bT + t0 + tid];
    zacc[tid] = 0.f;
  } else if (tid < 192) {
    scs[tid - 128] = sc[bT + s0 + (tid - 128)];
  }
  __syncthreads();

  ushort* base = Pfrag + (size_t)(b * 272 + cb) * 8192;
#pragma unroll
  for (int i = 0; i < 4; ++i) {
    const int run = tid * 4 + i;             // 0..1023, 8 elems each
    const int r  = ((run >> 7) << 4) | (run & 15);
    const int sb = (((run >> 6) & 1) << 5) | (((run >> 4) & 3) << 3);
    const float st = stv[r], pm = pmv[r];
    const int tg = t0 + r, sg0 = s0 + sb;
    ushort tmp[8];
    float z = 0.f;
#pragma unroll
    for (int k = 0; k < 8; ++k) {
      float pe = 0.f;
      if (sg0 + k <= tg) pe = __expf(st * (scs[sb + k] - pm));
      const ushort hb = f2bf(pe);
      tmp[k] = hb;
      z += bf2f(hb);
    }
    *(uint4*)(base + run * 8) = *(const uint4*)tmp;
    if (z != 0.f) atomicAdd(&zacc[r], z);
  }
  __syncthreads();
  if (tid < 128 && zacc[tid] != 0.f)
    atomicAdd(&Z[bT + t0 + tid], zacc[tid]);
}

// ---------------------------------------------------------------------------
// Attention = banded GEMM over pre-materialized P-frags. ZERO LDS, ZERO
// barriers: A-frags coalesced from Pfrag, B-frags from L2-resident valT,
// register double-buffered. Paired t-tiles (ty,15-ty): 34 chunks/block.
// Epilogue: multiply by 1/Z[t], store bf16 attnN.
// ---------------------------------------------------------------------------
__global__ __launch_bounds__(256, 2) void attn_gemm(
    const ushort* __restrict__ Pfrag, const ushort* __restrict__ valT,
    const float* __restrict__ Z, ushort* __restrict__ attnN)
{
  const int b = blockIdx.z;
  const int e0 = blockIdx.x * 128;
  const int tid = threadIdx.x;
  const int wave = tid >> 6, lane = tid & 63;
  const int l15 = lane & 15, lq = lane >> 4;
  const int wm = (wave & 1) * 64, wn = (wave >> 1) * 64;
  const int bT = b * T_SEQ;

#pragma unroll 1
  for (int ph = 0; ph < 2; ++ph) {
    const int ty = ph ? (int)blockIdx.y : 15 - (int)blockIdx.y;
    const int t0 = ty * 128;
    const int nch = 2 * ty + 2;                       // even
    const ushort* pb = Pfrag + (size_t)(b * 272 + ty * (ty + 1)) * 8192;

    size_t aoffs[4][2];
#pragma unroll
    for (int i = 0; i < 4; ++i)
#pragma unroll
      for (int ksi = 0; ksi < 2; ++ksi)
        aoffs[i][ksi] =
            (size_t)(((((wm >> 4) + i) * 2 + ksi) * 4 + lq) * 128 + l15 * 8);
    const ushort* vbase = valT + bT + lq * 8;
    size_t voffs[4];
#pragma unroll
    for (int j = 0; j < 4; ++j)
      voffs[j] = (size_t)(e0 + wn + j * 16 + l15) * R_ROWS;

    f32x4 acc[4][4] = {};
    short8 a0[4][2], v0[4][2], a1[4][2], v1[4][2];

    auto load = [&](short8 (&a)[4][2], short8 (&v)[4][2], int c) {
      const ushort* cbp = pb + (size_t)c * 8192;
      const ushort* vb = vbase + c * 64;
#pragma unroll
      for (int i = 0; i < 4; ++i) {
        a[i][0] = *(const short8*)(cbp + aoffs[i][0]);
        a[i][1] = *(const short8*)(cbp + aoffs[i][1]);
      }
#pragma unroll
      for (int j = 0; j < 4; ++j) {
        v[j][0] = *(const short8*)(vb + voffs[j]);
        v[j][1] = *(const short8*)(vb + voffs[j] + 32);
      }
    };
    auto step = [&](short8 (&a)[4][2], short8 (&v)[4][2]) {
#pragma unroll
      for (int ksi = 0; ksi < 2; ++ksi)
#pragma unroll
        for (int i = 0; i < 4; ++i)
#pragma unroll
          for (int j = 0; j < 4; ++j)
            acc[i][j] = __builtin_amdgcn_mfma_f32_16x16x32_bf16(
                a[i][ksi], v[j][ksi], acc[i][j], 0, 0, 0);
    };

    load(a0, v0, 0);
#pragma unroll 1
    for (int c = 0; c < nch; c += 2) {
      load(a1, v1, c + 1);
      step(a0, v0);
      if (c + 2 < nch) load(a0, v0, c + 2);
      step(a1, v1);
    }

#pragma unroll
    for (int i = 0; i < 4; ++i) {
      const int mlb = t0 + wm + i * 16 + lq * 4;
      float zi[4];
#pragma unroll
      for (int r = 0; r < 4; ++r) zi[r] = 1.0f / Z[bT + mlb + r];
#pragma unroll
      for (int j = 0; j < 4; ++j) {
        const int nb = e0 + wn + j * 16 + l15;
#pragma unroll
        for (int r = 0; r < 4; ++r)
          attnN[(size_t)(bT + mlb + r) * E_DIM + nb] = f2bf(acc[i][j][r] * zi[r]);
      }
    }
  }
}

// ---------------------------------------------------------------------------
// bf16 MFMA NT GEMM, B-side direct from fragment layout (unchanged).
// ---------------------------------------------------------------------------
template<bool OUT_BF16>
__global__ __launch_bounds__(256) void gemm_bf16_bfrag(
    const ushort* __restrict__ A, const ushort* __restrict__ Bf,
    void* __restrict__ Cout, int N, int K)
{
  __shared__ ushort As[128][40];
  const int tid = threadIdx.x;
  const int m0 = blockIdx.y * 128, n0 = blockIdx.x * 128;
  const int wave = tid >> 6, lane = tid & 63;
  const int l15 = lane & 15, lq = lane >> 4;
  const int wm = (wave & 1) * 64, wn = (wave >> 1) * 64;
  const int srow = tid >> 2, scol = (tid & 3) * 8;
  const int Kc = K >> 5;

  f32x4 acc[4][4] = {};
  const ushort* Ap = A + (size_t)(m0 + srow) * K + scol;
  size_t boff[4];
#pragma unroll
  for (int j = 0; j < 4; ++j)
    boff[j] = ((size_t)(((n0 + wn) >> 4) + j) * Kc * 4 + lq) * 128 + l15 * 8;

  for (int q = 0; q < Kc; ++q) {
    const uint4 a0 = *(const uint4*)(Ap + q * 32);
    const uint4 a1 = *(const uint4*)(Ap + (size_t)64 * K + q * 32);
    short8 bfr[4];
#pragma unroll
    for (int j = 0; j < 4; ++j)
      bfr[j] = *(const short8*)(Bf + boff[j] + (size_t)q * 512);
    __syncthreads();
    *(uint4*)&As[srow     ][scol] = a0;
    *(uint4*)&As[srow + 64][scol] = a1;
    __syncthreads();
    short8 af[4];
#pragma unroll
    for (int i = 0; i < 4; ++i)
      af[i] = *(const short8*)&As[wm + i*16 + l15][lq*8];
#pragma unroll
    for (int i = 0; i < 4; ++i)
#pragma unroll
      for (int j = 0; j < 4; ++j)
        acc[i][j] = __builtin_amdgcn_mfma_f32_16x16x32_bf16(af[i], bfr[j], acc[i][j], 0, 0, 0);
  }

#pragma unroll
  for (int i = 0; i < 4; ++i)
#pragma unroll
    for (int j = 0; j < 4; ++j) {
      const int mb = m0 + wm + i*16 + lq*4;
      const int nb = n0 + wn + j*16 + l15;
#pragma unroll
      for (int r = 0; r < 4; ++r) {
        if (OUT_BF16)
          ((ushort*)Cout)[(size_t)(mb + r) * N + nb] = f2bf(acc[i][j][r]);
        else
          ((float*)Cout)[(size_t)(mb + r) * N + nb] = acc[i][j][r];
      }
    }
}

// ---------------------------------------------------------------------------
extern "C" void kernel_launch(void* const* d_in, const int* in_sizes, int n_in,
                              void* d_out, int out_size, void* d_ws, size_t ws_size,
                              hipStream_t stream) {
  (void)in_sizes; (void)n_in; (void)out_size; (void)ws_size;
  const float* x   = (const float*)d_in[0];
  const float* wj  = (const float*)d_in[1];
  const float* wjv = (const float*)d_in[2];
  const float* wo  = (const float*)d_in[3];
  float* out = (float*)d_out;

  // Workspace (high-water ~53.1 MiB; 56.1 MiB proven available in round 3):
  ushort* xh_f  = (ushort*)d_ws;                        // 16 MiB (-> attnN)
  ushort* xl_f  = xh_f  + (size_t)R_ROWS * E_DIM;       // 16 MiB (-> valT)
  ushort* wjh_f = xl_f  + (size_t)R_ROWS * E_DIM;       // 2 MiB ┐ dead after sq
  ushort* wjl_f = wjh_f + (size_t)E_DIM * E_DIM;        // 2 MiB ┘
  ushort* Pfrag = wjh_f;                                // 17 MiB, post-sq alias
  float* sc_raw = (float*)(Pfrag + (size_t)1088 * 8192);
  float* Zbuf   = sc_raw + R_ROWS;
  float* sc     = Zbuf + R_ROWS;
  float* pmax   = sc + R_ROWS;
  ushort* wjvb  = (ushort*)(pmax + R_ROWS);             // 2 MiB row-major
  ushort* wob_f = wjvb + (size_t)E_DIM * E_DIM;         // 2 MiB frag
  ushort* valT  = xl_f;   // xl_f dead after gemm_sq_direct
  ushort* attnN = xh_f;   // xh_f dead after the val GEMM

  hipMemsetAsync(sc_raw, 0, 2 * R_ROWS * sizeof(float), stream);  // sc_raw + Z

  cvt_split_frag<<<R_ROWS*E_DIM/8/256, 256, 0, stream>>>(x,  xh_f,  xl_f,  R_ROWS*E_DIM/8);
  cvt_split_frag<<<E_DIM*E_DIM/8/256, 256, 0, stream>>>(wj, wjh_f, wjl_f, E_DIM*E_DIM/8);
  cvt_bf16<<<E_DIM*E_DIM/4/256, 256, 0, stream>>>(wjv, wjvb, E_DIM*E_DIM/4);
  cvt_bf16_frag<<<E_DIM*E_DIM/8/256, 256, 0, stream>>>(wo, wob_f, E_DIM*E_DIM/8);

  // sc_raw[r] = ||x_r @ wj^T||^2  (split-bf16 MFMA, LDS-free direct frags)
  gemm_sq_direct<<<dim3(E_DIM/128, R_ROWS/128), 256, 0, stream>>>(
      xh_f, xl_f, wjh_f, wjl_f, sc_raw);
  scan_max<<<4, 1024, 0, stream>>>(sc_raw, sc, pmax);

  // valT[e][r] = sum_k wjv[e][k] * x[r][k]   (A staged, B=x frag-direct)
  gemm_bf16_bfrag<true><<<dim3(R_ROWS/128, E_DIM/128), 256, 0, stream>>>(
      wjvb, xh_f, valT, R_ROWS, E_DIM);

  // materialize causal P band in A-frag layout + Z row sums (clobbers wjh/wjl)
  pgen<<<dim3(272, 4), 256, 0, stream>>>(sc, pmax, Pfrag, Zbuf);

  // attention = banded GEMM, normalized epilogue
  attn_gemm<<<dim3(E_DIM/128, 8, 4), 256, 0, stream>>>(Pfrag, valT, Zbuf, attnN);

  // out = attnN @ wo^T   (A staged, B=wo frag-direct, fp32 out)
  gemm_bf16_bfrag<false><<<dim3(E_DIM/128, R_ROWS/128), 256, 0, stream>>>(
      attnN, wob_f, out, E_DIM, E_DIM);
}

// Round 7
// 283.855 us; speedup vs baseline: 1.0274x; 1.0274x over previous
//
#include <hip/hip_runtime.h>
#include <math.h>

// B=4, T=2048, E=1024, H*D=1024; R = B*T = 8192.  K is always 1024.
#define R_ROWS 8192
#define T_SEQ  2048
#define E_DIM  1024
#define KC     32          // K/32 chunks

typedef __attribute__((ext_vector_type(8))) short short8;
typedef __attribute__((ext_vector_type(4))) float f32x4;

__device__ __forceinline__ ushort f2bf(float f) {
  uint u = __float_as_uint(f);
  u += 0x7FFFu + ((u >> 16) & 1u);   // round-to-nearest-even
  return (ushort)(u >> 16);
}
__device__ __forceinline__ float bf2f(ushort h) {
  return __uint_as_float(((uint)h) << 16);
}

// ---------------------------------------------------------------------------
// MFMA A/B fragment layout for a [R][1024] bf16 matrix:
//   off(r,k) = (((r>>4)*KC + (k>>5))*4 + ((k>>3)&3))*128 + (r&15)*8 + (k&7)
// ---------------------------------------------------------------------------

__global__ __launch_bounds__(256) void cvt_split_frag(
    const float* __restrict__ in, ushort* __restrict__ hi,
    ushort* __restrict__ lo, int n)
{
  int g = blockIdx.x * 256 + threadIdx.x;
  if (g >= n) return;
  const int l = g & 15, h = (g >> 4) & 3;
  const int pq = g >> 6;
  const int q = pq & (KC - 1), p = pq >> 5;
  const size_t src = (size_t)(p * 16 + l) * 1024 + q * 32 + h * 8;
  const float4 v0 = *(const float4*)&in[src];
  const float4 v1 = *(const float4*)&in[src + 4];
  ushort hh[8], ll[8];
  const float v[8] = {v0.x, v0.y, v0.z, v0.w, v1.x, v1.y, v1.z, v1.w};
#pragma unroll
  for (int e = 0; e < 8; ++e) {
    hh[e] = f2bf(v[e]);
    ll[e] = f2bf(v[e] - bf2f(hh[e]));
  }
  *(uint4*)&hi[(size_t)g * 8] = *(const uint4*)hh;
  *(uint4*)&lo[(size_t)g * 8] = *(const uint4*)ll;
}

__global__ __launch_bounds__(256) void cvt_bf16_frag(
    const float* __restrict__ in, ushort* __restrict__ out, int n)
{
  int g = blockIdx.x * 256 + threadIdx.x;
  if (g >= n) return;
  const int l = g & 15, h = (g >> 4) & 3;
  const int pq = g >> 6;
  const int q = pq & (KC - 1), p = pq >> 5;
  const size_t src = (size_t)(p * 16 + l) * 1024 + q * 32 + h * 8;
  const float4 v0 = *(const float4*)&in[src];
  const float4 v1 = *(const float4*)&in[src + 4];
  ushort hh[8];
  const float v[8] = {v0.x, v0.y, v0.z, v0.w, v1.x, v1.y, v1.z, v1.w};
#pragma unroll
  for (int e = 0; e < 8; ++e) hh[e] = f2bf(v[e]);
  *(uint4*)&out[(size_t)g * 8] = *(const uint4*)hh;
}

__global__ __launch_bounds__(256) void cvt_bf16(
    const float* __restrict__ in, ushort* __restrict__ out, int n4)
{
  int i = blockIdx.x * 256 + threadIdx.x;
  if (i >= n4) return;
  float4 v = ((const float4*)in)[i];
  ushort4 o;
  o.x = f2bf(v.x); o.y = f2bf(v.y); o.z = f2bf(v.z); o.w = f2bf(v.w);
  ((ushort4*)out)[i] = o;
}

// ---------------------------------------------------------------------------
// Split-bf16 sc kernel, LDS-free K-loop (unchanged from round 5).
// ---------------------------------------------------------------------------
struct Frags { short8 ah[4], al[4], bh[4], bl[4]; };

__global__ __launch_bounds__(256, 2) void gemm_sq_direct(
    const ushort* __restrict__ xh, const ushort* __restrict__ xl,
    const ushort* __restrict__ wh, const ushort* __restrict__ wl,
    float* __restrict__ sc_raw)
{
  const int tid = threadIdx.x;
  const int m0 = blockIdx.y * 128, n0 = blockIdx.x * 128;
  const int wave = tid >> 6, lane = tid & 63;
  const int l15 = lane & 15, lq = lane >> 4;
  const int wm = (wave & 1) * 64, wn = (wave >> 1) * 64;

  size_t aoff[4], boff[4];
#pragma unroll
  for (int i = 0; i < 4; ++i)
    aoff[i] = ((size_t)(((m0 + wm) >> 4) + i) * KC * 4 + lq) * 128 + l15 * 8;
#pragma unroll
  for (int j = 0; j < 4; ++j)
    boff[j] = ((size_t)(((n0 + wn) >> 4) + j) * KC * 4 + lq) * 128 + l15 * 8;

  f32x4 acc[4][4] = {};
  Frags f0, f1;

  auto load = [&](Frags& f, int q) {
    const size_t dq = (size_t)q * 512;
#pragma unroll
    for (int i = 0; i < 4; ++i) {
      f.ah[i] = *(const short8*)(xh + aoff[i] + dq);
      f.al[i] = *(const short8*)(xl + aoff[i] + dq);
    }
#pragma unroll
    for (int j = 0; j < 4; ++j) {
      f.bh[j] = *(const short8*)(wh + boff[j] + dq);
      f.bl[j] = *(const short8*)(wl + boff[j] + dq);
    }
  };
  auto step = [&](const Frags& f) {
#pragma unroll
    for (int i = 0; i < 4; ++i)
#pragma unroll
      for (int j = 0; j < 4; ++j) {
        acc[i][j] = __builtin_amdgcn_mfma_f32_16x16x32_bf16(f.ah[i], f.bh[j], acc[i][j], 0, 0, 0);
        acc[i][j] = __builtin_amdgcn_mfma_f32_16x16x32_bf16(f.ah[i], f.bl[j], acc[i][j], 0, 0, 0);
        acc[i][j] = __builtin_amdgcn_mfma_f32_16x16x32_bf16(f.al[i], f.bh[j], acc[i][j], 0, 0, 0);
      }
  };

  load(f0, 0);
#pragma unroll 1
  for (int q = 0; q < KC; q += 2) {
    load(f1, q + 1);
    step(f0);
    if (q + 2 < KC) load(f0, q + 2);
    step(f1);
  }

  __shared__ float red[128][33];
#pragma unroll
  for (int i = 0; i < 4; ++i)
#pragma unroll
    for (int r = 0; r < 4; ++r) {
      const int row = wm + i * 16 + lq * 4 + r;
      float s = 0.f;
#pragma unroll
      for (int j = 0; j < 4; ++j) s += acc[i][j][r] * acc[i][j][r];
      red[row][(l15 << 1) | (wave >> 1)] = s;
    }
  __syncthreads();
  if (tid < 128) {
    float s = 0.f;
#pragma unroll
    for (int c = 0; c < 32; ++c) s += red[tid][c];
    atomicAdd(&sc_raw[m0 + tid], s);
  }
}

// ---------------------------------------------------------------------------
// sc = sc_raw/32; pmax = inclusive prefix max per batch.
// ---------------------------------------------------------------------------
__global__ __launch_bounds__(1024) void scan_max(
    const float* __restrict__ sc_raw, float* __restrict__ sc,
    float* __restrict__ pmax)
{
  const int b = blockIdx.x;
  __shared__ float b0[T_SEQ];
  __shared__ float b1[T_SEQ];
  const int tid = threadIdx.x;
  for (int i = tid; i < T_SEQ; i += 1024) {
    const float v = sc_raw[b*T_SEQ + i] * 0.03125f;
    b0[i] = v;
    sc[b*T_SEQ + i] = v;
  }
  __syncthreads();
  float* src = b0; float* dst = b1;
  for (int off = 1; off < T_SEQ; off <<= 1) {
    for (int i = tid; i < T_SEQ; i += 1024)
      dst[i] = (i >= off) ? fmaxf(src[i], src[i - off]) : src[i];
    __syncthreads();
    float* tmp = src; src = dst; dst = tmp;
  }
  for (int i = tid; i < T_SEQ; i += 1024) pmax[b*T_SEQ + i] = src[i];
}

// ---------------------------------------------------------------------------
// bf16 MFMA NT GEMM, B-side direct from fragment layout (unchanged).
// ---------------------------------------------------------------------------
template<bool OUT_BF16>
__global__ __launch_bounds__(256) void gemm_bf16_bfrag(
    const ushort* __restrict__ A, const ushort* __restrict__ Bf,
    void* __restrict__ Cout, int N, int K)
{
  __shared__ ushort As[128][40];
  const int tid = threadIdx.x;
  const int m0 = blockIdx.y * 128, n0 = blockIdx.x * 128;
  const int wave = tid >> 6, lane = tid & 63;
  const int l15 = lane & 15, lq = lane >> 4;
  const int wm = (wave & 1) * 64, wn = (wave >> 1) * 64;
  const int srow = tid >> 2, scol = (tid & 3) * 8;
  const int Kc = K >> 5;

  f32x4 acc[4][4] = {};
  const ushort* Ap = A + (size_t)(m0 + srow) * K + scol;
  size_t boff[4];
#pragma unroll
  for (int j = 0; j < 4; ++j)
    boff[j] = ((size_t)(((n0 + wn) >> 4) + j) * Kc * 4 + lq) * 128 + l15 * 8;

  for (int q = 0; q < Kc; ++q) {
    const uint4 a0 = *(const uint4*)(Ap + q * 32);
    const uint4 a1 = *(const uint4*)(Ap + (size_t)64 * K + q * 32);
    short8 bfr[4];
#pragma unroll
    for (int j = 0; j < 4; ++j)
      bfr[j] = *(const short8*)(Bf + boff[j] + (size_t)q * 512);
    __syncthreads();
    *(uint4*)&As[srow     ][scol] = a0;
    *(uint4*)&As[srow + 64][scol] = a1;
    __syncthreads();
    short8 af[4];
#pragma unroll
    for (int i = 0; i < 4; ++i)
      af[i] = *(const short8*)&As[wm + i*16 + l15][lq*8];
#pragma unroll
    for (int i = 0; i < 4; ++i)
#pragma unroll
      for (int j = 0; j < 4; ++j)
        acc[i][j] = __builtin_amdgcn_mfma_f32_16x16x32_bf16(af[i], bfr[j], acc[i][j], 0, 0, 0);
  }

#pragma unroll
  for (int i = 0; i < 4; ++i)
#pragma unroll
    for (int j = 0; j < 4; ++j) {
      const int mb = m0 + wm + i*16 + lq*4;
      const int nb = n0 + wn + j*16 + l15;
#pragma unroll
      for (int r = 0; r < 4; ++r) {
        if (OUT_BF16)
          ((ushort*)Cout)[(size_t)(mb + r) * N + nb] = f2bf(acc[i][j][r]);
        else
          ((float*)Cout)[(size_t)(mb + r) * N + nb] = acc[i][j][r];
      }
    }
}

// ---------------------------------------------------------------------------
// Fused causal rank-1 attention, in-LDS P regeneration (round-5 structure)
// retiled to 64t x 256e: exp redundancy 8x -> 4x, V traffic served by L1/L2.
// 512 thr / 8 waves (2 t-waves x 4 e-waves, each 32t x 64e, acc[2][4]).
// Pairs (ty, 31-ty) of 64-row tiles: every block exactly 33 chunks.
// P double-buffered in LDS, one barrier per chunk; V-frags dbuf in regs from
// L2-resident valT [E][R]. Causal mask only on the diagonal chunk.
// ---------------------------------------------------------------------------
__global__ __launch_bounds__(512) void attn_mfma(
    const ushort* __restrict__ valT, const float* __restrict__ sc,
    const float* __restrict__ pmax, ushort* __restrict__ attnN)
{
  __shared__ float scs_all[T_SEQ];     // 8 KB
  __shared__ ushort p[2][64][72];      // 18.4 KB dbuf P (bf16)
  __shared__ float zsh[64][9];
  __shared__ float zinv[64];

  const int b  = blockIdx.z;
  const int e0 = blockIdx.x * 256;
  const int tid = threadIdx.x;
  const int wave = tid >> 6, lane = tid & 63;
  const int l15 = lane & 15, lq = lane >> 4;
  const int wm = (wave & 1) * 32;      // t-offset of wave
  const int wn = (wave >> 1) * 64;     // e-offset of wave
  const int bT = b * T_SEQ;

  *(float4*)&scs_all[tid * 4] = *(const float4*)&sc[bT + tid * 4];
  __syncthreads();

  const int prow = tid >> 3;           // 0..63
  const int pc = (tid & 7) * 8;        // 0..56

#pragma unroll 1
  for (int ph = 0; ph < 2; ++ph) {
    const int ty = ph ? (int)blockIdx.y : 31 - (int)blockIdx.y;
    const int t0 = ty * 64;
    const int nch = ty + 1;

    const float st = scs_all[t0 + prow];
    const float nd = -st * pmax[bT + t0 + prow];
    const int tglob = t0 + prow;

    f32x4 acc[2][4] = {};
    float zp = 0.f;

    auto pgen = [&](int c, int buf) -> float {
      const int s0 = c * 64;
      float sv[8];
      *(float4*)&sv[0] = *(const float4*)&scs_all[s0 + pc];
      *(float4*)&sv[4] = *(const float4*)&scs_all[s0 + pc + 4];
      ushort tmp[8];
      float z = 0.f;
      if (c < nch - 1) {               // full chunk: no causal mask
#pragma unroll
        for (int k = 0; k < 8; ++k) {
          const float pe = __expf(fmaf(st, sv[k], nd));
          const ushort h = f2bf(pe);
          tmp[k] = h;
          z += bf2f(h);
        }
      } else {                         // diagonal chunk
        const int sg0 = s0 + pc;
#pragma unroll
        for (int k = 0; k < 8; ++k) {
          float pe = 0.f;
          if (sg0 + k <= tglob) pe = __expf(fmaf(st, sv[k], nd));
          const ushort h = f2bf(pe);
          tmp[k] = h;
          z += bf2f(h);
        }
      }
      *(uint4*)&p[buf][prow][pc] = *(const uint4*)tmp;
      return z;
    };

    auto loadB = [&](short8* dst, int c) {
#pragma unroll
      for (int j = 0; j < 4; ++j)
#pragma unroll
        for (int ksi = 0; ksi < 2; ++ksi)
          dst[j*2 + ksi] = *(const short8*)&valT[
              (size_t)(e0 + wn + j*16 + l15) * R_ROWS + bT + c*64 + ksi*32 + lq*8];
    };

    auto mstep = [&](int buf, const short8* bfr) {
#pragma unroll
      for (int ksi = 0; ksi < 2; ++ksi) {
        short8 af[2];
#pragma unroll
        for (int i = 0; i < 2; ++i)
          af[i] = *(const short8*)&p[buf][wm + i*16 + l15][ksi*32 + lq*8];
#pragma unroll
        for (int i = 0; i < 2; ++i)
#pragma unroll
          for (int j = 0; j < 4; ++j)
            acc[i][j] = __builtin_amdgcn_mfma_f32_16x16x32_bf16(
                af[i], bfr[j*2 + ksi], acc[i][j], 0, 0, 0);
      }
    };

    short8 bA[8], bB[8];
    zp += pgen(0, 0);
    loadB(bA, 0);
    __syncthreads();

#pragma unroll 1
    for (int c = 0; c < nch; ++c) {
      if ((c & 1) == 0) {
        if (c + 1 < nch) { loadB(bB, c + 1); zp += pgen(c + 1, 1); }
        mstep(0, bA);
      } else {
        if (c + 1 < nch) { loadB(bA, c + 1); zp += pgen(c + 1, 0); }
        mstep(1, bB);
      }
      __syncthreads();
    }

    // Z reduce (8 partials per t-row) + normalize + store
    zsh[prow][tid & 7] = zp;
    __syncthreads();
    if (tid < 64) {
      float z = 0.f;
#pragma unroll
      for (int q = 0; q < 8; ++q) z += zsh[tid][q];
      zinv[tid] = 1.0f / z;
    }
    __syncthreads();

#pragma unroll
    for (int i = 0; i < 2; ++i)
#pragma unroll
      for (int j = 0; j < 4; ++j) {
        const int nb = e0 + wn + j*16 + l15;
#pragma unroll
        for (int r = 0; r < 4; ++r) {
          const int ml = wm + i*16 + lq*4 + r;
          const float v = acc[i][j][r] * zinv[ml];
          attnN[(size_t)(bT + t0 + ml) * E_DIM + nb] = f2bf(v);
        }
      }
    __syncthreads();   // zsh/zinv/p safe before next phase
  }
}

// ---------------------------------------------------------------------------
extern "C" void kernel_launch(void* const* d_in, const int* in_sizes, int n_in,
                              void* d_out, int out_size, void* d_ws, size_t ws_size,
                              hipStream_t stream) {
  (void)in_sizes; (void)n_in; (void)out_size; (void)ws_size;
  const float* x   = (const float*)d_in[0];
  const float* wj  = (const float*)d_in[1];
  const float* wjv = (const float*)d_in[2];
  const float* wo  = (const float*)d_in[3];
  float* out = (float*)d_out;

  ushort* xh_f  = (ushort*)d_ws;                        // 16 MB frag
  ushort* xl_f  = xh_f  + (size_t)R_ROWS * E_DIM;       // 16 MB frag
  ushort* wjh_f = xl_f  + (size_t)R_ROWS * E_DIM;       // 2 MB frag
  ushort* wjl_f = wjh_f + (size_t)E_DIM * E_DIM;        // 2 MB frag
  ushort* wjvb  = wjl_f + (size_t)E_DIM * E_DIM;        // 2 MB row-major
  ushort* wob_f = wjvb  + (size_t)E_DIM * E_DIM;        // 2 MB frag
  float* sc_raw = (float*)(wob_f + (size_t)E_DIM * E_DIM);
  float* sc     = sc_raw + R_ROWS;
  float* pmax   = sc + R_ROWS;
  ushort* valT  = xl_f;   // xl_f dead after gemm_sq_direct (stream-serial)
  ushort* attnN = xh_f;   // xh_f dead after the val GEMM

  hipMemsetAsync(sc_raw, 0, R_ROWS * sizeof(float), stream);

  cvt_split_frag<<<R_ROWS*E_DIM/8/256, 256, 0, stream>>>(x,  xh_f,  xl_f,  R_ROWS*E_DIM/8);
  cvt_split_frag<<<E_DIM*E_DIM/8/256, 256, 0, stream>>>(wj, wjh_f, wjl_f, E_DIM*E_DIM/8);
  cvt_bf16<<<E_DIM*E_DIM/4/256, 256, 0, stream>>>(wjv, wjvb, E_DIM*E_DIM/4);
  cvt_bf16_frag<<<E_DIM*E_DIM/8/256, 256, 0, stream>>>(wo, wob_f, E_DIM*E_DIM/8);

  // sc_raw[r] = ||x_r @ wj^T||^2  (split-bf16 MFMA, LDS-free direct frags)
  gemm_sq_direct<<<dim3(E_DIM/128, R_ROWS/128), 256, 0, stream>>>(
      xh_f, xl_f, wjh_f, wjl_f, sc_raw);
  scan_max<<<4, 1024, 0, stream>>>(sc_raw, sc, pmax);

  // valT[e][r] = sum_k wjv[e][k] * x[r][k]   (A staged, B=x frag-direct)
  gemm_bf16_bfrag<true><<<dim3(R_ROWS/128, E_DIM/128), 256, 0, stream>>>(
      wjvb, xh_f, valT, R_ROWS, E_DIM);

  // normalized attention, 64t x 256e tiles, pairs (ty,31-ty): grid 4x16x4
  attn_mfma<<<dim3(E_DIM/256, 16, 4), 512, 0, stream>>>(valT, sc, pmax, attnN);

  // out = attnN @ wo^T   (A staged, B=wo frag-direct, fp32 out)
  gemm_bf16_bfrag<false><<<dim3(E_DIM/128, R_ROWS/128), 256, 0, stream>>>(
      attnN, wob_f, out, E_DIM, E_DIM);
}